// Round 2
// baseline (2539.905 us; speedup 1.0000x reference)
//
#include <hip/hip_runtime.h>

#define NODES 50000
#define EDGES 800000
#define H 96

typedef float floatx4 __attribute__((ext_vector_type(4)));
typedef float floatx2 __attribute__((ext_vector_type(2)));

static __device__ __forceinline__ float gelu_erf(float x) {
    return 0.5f * x * (1.0f + erff(x * 0.70710678118654752f));
}

// out[r,c] = gelu(sum_k A[r,k]*W[k,c] + bias[c]) (+ resid[r,c])
// Block 256 threads, 64 rows per block. W (96x96 fp32, 36 KB) staged in LDS;
// A-tile stored k-major with pad 68 (68*4=272B row stride: keeps 16B alignment
// for ds_read_b128 and spreads banks).
__global__ __launch_bounds__(256) void gemm96f(
    const float* __restrict__ A,
    const float* __restrict__ W,
    const float* __restrict__ bias,
    const float* __restrict__ resid,
    float* __restrict__ out,
    int nRows)
{
    __shared__ float As[96][68];
    __shared__ float Wl[96][96];
    const int tid  = threadIdx.x;
    const int row0 = blockIdx.x * 64;

    // stage W: 9216 floats = 2304 float4, 9 per thread (coalesced, conflict-free)
    #pragma unroll
    for (int j = 0; j < 9; ++j) {
        const int f = tid + 256 * j;            // < 2304
        const floatx4 v = *(const floatx4*)(W + (size_t)f * 4);
        const int k = (f * 4) / 96, c = (f * 4) % 96;
        *(floatx4*)(&Wl[k][c]) = v;
    }
    // stage A transposed: 64 rows x 24 float4 = 1536 float4, 6 per thread
    #pragma unroll
    for (int j = 0; j < 6; ++j) {
        const int f  = tid + 256 * j;           // < 1536
        const int r  = f / 24, k4 = f % 24;
        int rr = row0 + r; if (rr >= nRows) rr = nRows - 1;   // clamp (writes guarded later)
        const floatx4 v = *(const floatx4*)(A + (size_t)rr * H + k4 * 4);
        As[k4 * 4 + 0][r] = v[0];
        As[k4 * 4 + 1][r] = v[1];
        As[k4 * 4 + 2][r] = v[2];
        As[k4 * 4 + 3][r] = v[3];
    }
    __syncthreads();

    const int rgrp = tid & 15;    // rows rgrp*4 .. +3
    const int cgrp = tid >> 4;    // cols cgrp*6 .. +5
    const int c0   = cgrp * 6;

    float breg[6];
    #pragma unroll
    for (int j = 0; j < 6; ++j) breg[j] = bias[c0 + j];

    float acc[4][6];
    #pragma unroll
    for (int i = 0; i < 4; ++i)
        #pragma unroll
        for (int j = 0; j < 6; ++j) acc[i][j] = 0.0f;

    #pragma unroll 4
    for (int k = 0; k < 96; ++k) {
        const floatx4 a = *(const floatx4*)(&As[k][rgrp * 4]);   // 16B aligned
        const floatx2 w01 = *(const floatx2*)(&Wl[k][c0]);
        const floatx2 w23 = *(const floatx2*)(&Wl[k][c0 + 2]);
        const floatx2 w45 = *(const floatx2*)(&Wl[k][c0 + 4]);
        const float w[6] = { w01[0], w01[1], w23[0], w23[1], w45[0], w45[1] };
        #pragma unroll
        for (int i = 0; i < 4; ++i)
            #pragma unroll
            for (int j = 0; j < 6; ++j)
                acc[i][j] = fmaf(a[i], w[j], acc[i][j]);
    }

    #pragma unroll
    for (int i = 0; i < 4; ++i) {
        const int row = row0 + rgrp * 4 + i;
        if (row >= nRows) continue;
        #pragma unroll
        for (int j = 0; j < 6; ++j) {
            float g = gelu_erf(acc[i][j] + breg[j]);
            if (resid) g += resid[(size_t)row * H + c0 + j];
            out[(size_t)row * H + c0 + j] = g;
        }
    }
}

// aggr[dst[e]] += h[src[e]] * bases[e]   (fp32 atomics)
// 12 threads per edge, 8 floats each.
__global__ __launch_bounds__(256) void edge_scatter(
    const float* __restrict__ h,
    const float* __restrict__ bases,
    const int* __restrict__ src,
    const int* __restrict__ dst,
    float* __restrict__ aggr)
{
    const int t = blockIdx.x * 256 + threadIdx.x;
    const int e = t / 12;
    const int seg = t - e * 12;
    if (e >= EDGES) return;
    const int s = src[e];
    const int d = dst[e];
    const size_t eo = (size_t)e * H + seg * 8;
    const size_t so = (size_t)s * H + seg * 8;
    const floatx4 b0 = *(const floatx4*)(bases + eo);
    const floatx4 b1 = *(const floatx4*)(bases + eo + 4);
    const floatx4 h0 = *(const floatx4*)(h + so);
    const floatx4 h1 = *(const floatx4*)(h + so + 4);
    float* ap = aggr + (size_t)d * H + seg * 8;
    #pragma unroll
    for (int j = 0; j < 4; ++j) atomicAdd(ap + j,     b0[j] * h0[j]);
    #pragma unroll
    for (int j = 0; j < 4; ++j) atomicAdd(ap + 4 + j, b1[j] * h1[j]);
}

// xo = xf + aggr (fp32, float4)
__global__ __launch_bounds__(256) void resid_add(
    const float* __restrict__ xf,
    const float* __restrict__ aggr,
    float* __restrict__ xo)
{
    const size_t i = (size_t)(blockIdx.x * 256 + threadIdx.x) * 4;
    if (i >= (size_t)NODES * H) return;
    const floatx4 a = *(const floatx4*)(xf + i);
    const floatx4 b = *(const floatx4*)(aggr + i);
    floatx4 o;
    #pragma unroll
    for (int j = 0; j < 4; ++j) o[j] = a[j] + b[j];
    *(floatx4*)(xo + i) = o;
}

extern "C" void kernel_launch(void* const* d_in, const int* in_sizes, int n_in,
                              void* d_out, int out_size, void* d_ws, size_t ws_size,
                              hipStream_t stream)
{
    const float* x_feat = (const float*)d_in[0];
    const float* bases  = (const float*)d_in[1];
    const float* W_pre  = (const float*)d_in[2];
    const float* b_pre  = (const float*)d_in[3];
    const float* W1     = (const float*)d_in[4];
    const float* b1     = (const float*)d_in[5];
    const float* W2     = (const float*)d_in[6];
    const float* b2     = (const float*)d_in[7];
    const int* src = (const int*)d_in[8];
    const int* dst = (const int*)d_in[9];

    char* ws = (char*)d_ws;
    float* hbuf = (float*)(ws);                      // 19.2 MB (reused as tbuf)
    float* aggr = (float*)(ws + 19200000);           // 19.2 MB
    float* xb   = (float*)(ws + 38400000);           // 19.2 MB
    float* tbuf = hbuf;                              // alias: hbuf dead after scatter
    float* out  = (float*)d_out;

    hipMemsetAsync(aggr, 0, (size_t)NODES * H * sizeof(float), stream);

    const int gemmGrid = (NODES + 63) / 64;  // 782
    // h = gelu(x_feat @ W_pre + b_pre)
    gemm96f<<<gemmGrid, 256, 0, stream>>>(x_feat, W_pre, b_pre, nullptr, hbuf, NODES);
    // aggr = scatter_sum(h[src] * bases, dst)
    edge_scatter<<<(EDGES * 12 + 255) / 256, 256, 0, stream>>>(hbuf, bases, src, dst, aggr);
    // x = x_feat + aggr
    resid_add<<<(NODES * H / 4 + 255) / 256, 256, 0, stream>>>(x_feat, aggr, xb);
    // t = gelu(x @ W1 + b1)
    gemm96f<<<gemmGrid, 256, 0, stream>>>(xb, W1, b1, nullptr, tbuf, NODES);
    // out = x + gelu(t @ W2 + b2)
    gemm96f<<<gemmGrid, 256, 0, stream>>>(tbuf, W2, b2, xb, out, NODES);
}

// Round 3
// 770.288 us; speedup vs baseline: 3.2973x; 3.2973x over previous
//
#include <hip/hip_runtime.h>

#define NODES 50000
#define EDGES 800000
#define H 96

typedef float floatx4 __attribute__((ext_vector_type(4)));
typedef float floatx2 __attribute__((ext_vector_type(2)));

static __device__ __forceinline__ float gelu_erf(float x) {
    return 0.5f * x * (1.0f + erff(x * 0.70710678118654752f));
}

// ---------------- GEMM (unchanged from R2; target for next round) -----------
__global__ __launch_bounds__(256) void gemm96f(
    const float* __restrict__ A,
    const float* __restrict__ W,
    const float* __restrict__ bias,
    const float* __restrict__ resid,
    float* __restrict__ out,
    int nRows)
{
    __shared__ float As[96][68];
    __shared__ float Wl[96][96];
    const int tid  = threadIdx.x;
    const int row0 = blockIdx.x * 64;

    #pragma unroll
    for (int j = 0; j < 9; ++j) {
        const int f = tid + 256 * j;
        const floatx4 v = *(const floatx4*)(W + (size_t)f * 4);
        const int k = (f * 4) / 96, c = (f * 4) % 96;
        *(floatx4*)(&Wl[k][c]) = v;
    }
    #pragma unroll
    for (int j = 0; j < 6; ++j) {
        const int f  = tid + 256 * j;
        const int r  = f / 24, k4 = f % 24;
        int rr = row0 + r; if (rr >= nRows) rr = nRows - 1;
        const floatx4 v = *(const floatx4*)(A + (size_t)rr * H + k4 * 4);
        As[k4 * 4 + 0][r] = v[0];
        As[k4 * 4 + 1][r] = v[1];
        As[k4 * 4 + 2][r] = v[2];
        As[k4 * 4 + 3][r] = v[3];
    }
    __syncthreads();

    const int rgrp = tid & 15;
    const int cgrp = tid >> 4;
    const int c0   = cgrp * 6;

    float breg[6];
    #pragma unroll
    for (int j = 0; j < 6; ++j) breg[j] = bias[c0 + j];

    float acc[4][6];
    #pragma unroll
    for (int i = 0; i < 4; ++i)
        #pragma unroll
        for (int j = 0; j < 6; ++j) acc[i][j] = 0.0f;

    #pragma unroll 4
    for (int k = 0; k < 96; ++k) {
        const floatx4 a = *(const floatx4*)(&As[k][rgrp * 4]);
        const floatx2 w01 = *(const floatx2*)(&Wl[k][c0]);
        const floatx2 w23 = *(const floatx2*)(&Wl[k][c0 + 2]);
        const floatx2 w45 = *(const floatx2*)(&Wl[k][c0 + 4]);
        const float w[6] = { w01[0], w01[1], w23[0], w23[1], w45[0], w45[1] };
        #pragma unroll
        for (int i = 0; i < 4; ++i)
            #pragma unroll
            for (int j = 0; j < 6; ++j)
                acc[i][j] = fmaf(a[i], w[j], acc[i][j]);
    }

    #pragma unroll
    for (int i = 0; i < 4; ++i) {
        const int row = row0 + rgrp * 4 + i;
        if (row >= nRows) continue;
        #pragma unroll
        for (int j = 0; j < 6; ++j) {
            float g = gelu_erf(acc[i][j] + breg[j]);
            if (resid) g += resid[(size_t)row * H + c0 + j];
            out[(size_t)row * H + c0 + j] = g;
        }
    }
}

// ---------------- CSR build: histogram -> scan -> cursor scatter ------------
__global__ __launch_bounds__(256) void hist_deg(
    const int* __restrict__ dst, int* __restrict__ deg)
{
    const int e = blockIdx.x * 256 + threadIdx.x;
    if (e < EDGES) atomicAdd(&deg[dst[e]], 1);
}

__global__ __launch_bounds__(1024) void scan_deg(
    const int* __restrict__ deg, int* __restrict__ off, int* __restrict__ cursor)
{
    __shared__ int part[1024];
    const int tid = threadIdx.x;
    const int CH  = (NODES + 1023) / 1024;          // 49
    const int lo  = tid * CH;
    const int hi  = min(lo + CH, NODES);
    int s = 0;
    for (int i = lo; i < hi; ++i) s += deg[i];
    part[tid] = s;
    __syncthreads();
    for (int d = 1; d < 1024; d <<= 1) {
        int v = (tid >= d) ? part[tid - d] : 0;
        __syncthreads();
        part[tid] += v;
        __syncthreads();
    }
    int run = (tid == 0) ? 0 : part[tid - 1];
    for (int i = lo; i < hi; ++i) {
        off[i] = run; cursor[i] = run;
        run += deg[i];
    }
    if (tid == 1023) off[NODES] = part[1023];       // = EDGES
}

__global__ __launch_bounds__(256) void build_csr(
    const int* __restrict__ dst, int* __restrict__ cursor, int* __restrict__ csr)
{
    const int e = blockIdx.x * 256 + threadIdx.x;
    if (e < EDGES) {
        const int p = atomicAdd(&cursor[dst[e]], 1);
        csr[p] = e;
    }
}

// ---------------- Pull-aggregate, fused residual: xb = x_feat + sum ---------
// 12 threads per node, 8 floats each. No float atomics.
__global__ __launch_bounds__(256) void gather_nodes(
    const float* __restrict__ h,
    const float* __restrict__ bases,
    const int* __restrict__ src,
    const int* __restrict__ off,
    const int* __restrict__ csr,
    const float* __restrict__ x_feat,
    float* __restrict__ xb)
{
    const int t = blockIdx.x * 256 + threadIdx.x;
    const int n = t / 12;
    const int seg = t - n * 12;
    if (n >= NODES) return;
    const int i0 = off[n], i1 = off[n + 1];
    const int so8 = seg * 8;

    floatx4 acc0 = (floatx4){0.f, 0.f, 0.f, 0.f};
    floatx4 acc1 = (floatx4){0.f, 0.f, 0.f, 0.f};
    for (int i = i0; i < i1; ++i) {
        const int e = csr[i];
        const int s = src[e];
        const size_t eo = (size_t)e * H + so8;
        const size_t so = (size_t)s * H + so8;
        const floatx4 b0 = *(const floatx4*)(bases + eo);
        const floatx4 b1 = *(const floatx4*)(bases + eo + 4);
        const floatx4 h0 = *(const floatx4*)(h + so);
        const floatx4 h1 = *(const floatx4*)(h + so + 4);
        #pragma unroll
        for (int j = 0; j < 4; ++j) acc0[j] = fmaf(b0[j], h0[j], acc0[j]);
        #pragma unroll
        for (int j = 0; j < 4; ++j) acc1[j] = fmaf(b1[j], h1[j], acc1[j]);
    }

    const size_t no = (size_t)n * H + so8;
    const floatx4 x0 = *(const floatx4*)(x_feat + no);
    const floatx4 x1 = *(const floatx4*)(x_feat + no + 4);
    #pragma unroll
    for (int j = 0; j < 4; ++j) acc0[j] += x0[j];
    #pragma unroll
    for (int j = 0; j < 4; ++j) acc1[j] += x1[j];
    *(floatx4*)(xb + no)     = acc0;
    *(floatx4*)(xb + no + 4) = acc1;
}

extern "C" void kernel_launch(void* const* d_in, const int* in_sizes, int n_in,
                              void* d_out, int out_size, void* d_ws, size_t ws_size,
                              hipStream_t stream)
{
    const float* x_feat = (const float*)d_in[0];
    const float* bases  = (const float*)d_in[1];
    const float* W_pre  = (const float*)d_in[2];
    const float* b_pre  = (const float*)d_in[3];
    const float* W1     = (const float*)d_in[4];
    const float* b1     = (const float*)d_in[5];
    const float* W2     = (const float*)d_in[6];
    const float* b2     = (const float*)d_in[7];
    const int* src = (const int*)d_in[8];
    const int* dst = (const int*)d_in[9];

    char* ws = (char*)d_ws;
    int*   deg    = (int*)(ws);                      // 200,000 B
    int*   off    = (int*)(ws + 200064);             // 200,004 B
    int*   cursor = (int*)(ws + 400128);             // 200,000 B
    int*   csr    = (int*)(ws + 600192);             // 3,200,000 B
    float* hbuf   = (float*)(ws + 3800192);          // 19.2 MB (reused as tbuf)
    float* xb     = (float*)(ws + 23000192);         // 19.2 MB
    float* tbuf   = hbuf;
    float* out    = (float*)d_out;

    hipMemsetAsync(deg, 0, NODES * sizeof(int), stream);

    const int gemmGrid = (NODES + 63) / 64;  // 782
    // h = gelu(x_feat @ W_pre + b_pre)   (overlap-free but CSR build is independent;
    // stream order: build CSR while nothing depends on it yet)
    hist_deg<<<(EDGES + 255) / 256, 256, 0, stream>>>(dst, deg);
    scan_deg<<<1, 1024, 0, stream>>>(deg, off, cursor);
    build_csr<<<(EDGES + 255) / 256, 256, 0, stream>>>(dst, cursor, csr);
    gemm96f<<<gemmGrid, 256, 0, stream>>>(x_feat, W_pre, b_pre, nullptr, hbuf, NODES);
    // xb = x_feat + scatter_sum(h[src]*bases, dst)   (pull form, no atomics)
    gather_nodes<<<(NODES * 12 + 255) / 256, 256, 0, stream>>>(
        hbuf, bases, src, off, csr, x_feat, xb);
    // t = gelu(xb @ W1 + b1)
    gemm96f<<<gemmGrid, 256, 0, stream>>>(xb, W1, b1, nullptr, tbuf, NODES);
    // out = xb + gelu(t @ W2 + b2)
    gemm96f<<<gemmGrid, 256, 0, stream>>>(tbuf, W2, b2, xb, out, NODES);
}

// Round 4
// 722.858 us; speedup vs baseline: 3.5137x; 1.0656x over previous
//
#include <hip/hip_runtime.h>

#define NODES 50000
#define EDGES 800000
#define H 96

typedef float floatx4 __attribute__((ext_vector_type(4)));
typedef unsigned short ushort8 __attribute__((ext_vector_type(8)));
typedef __bf16 bf16x8 __attribute__((ext_vector_type(8)));

static __device__ __forceinline__ unsigned short f2b(float f) {
    unsigned int u = __float_as_uint(f);
    u = u + 0x7fffu + ((u >> 16) & 1u);   // RNE
    return (unsigned short)(u >> 16);
}
static __device__ __forceinline__ float b2f(unsigned short u) {
    return __uint_as_float(((unsigned int)u) << 16);
}
static __device__ __forceinline__ float gelu_erf(float x) {
    return 0.5f * x * (1.0f + erff(x * 0.70710678118654752f));
}

// fp32 -> bf16, 8 elems/thread
__global__ __launch_bounds__(256) void cvt_bf16(
    const float* __restrict__ in, unsigned short* __restrict__ out, int n8)
{
    const int i = blockIdx.x * 256 + threadIdx.x;
    if (i >= n8) return;
    const floatx4 a = *(const floatx4*)(in + (size_t)i * 8);
    const floatx4 b = *(const floatx4*)(in + (size_t)i * 8 + 4);
    ushort8 o;
    #pragma unroll
    for (int j = 0; j < 4; ++j) { o[j] = f2b(a[j]); o[4 + j] = f2b(b[j]); }
    *(ushort8*)(out + (size_t)i * 8) = o;
}

// ---------------- MFMA GEMM: out = gelu(A@W + b) [+ resid] ------------------
// A: bf16 [nRows][96]. W: fp32 [96][96] k-major, staged to LDS transposed bf16.
// mfma_f32_16x16x32_bf16: A frag A[m=lane&15][k=quad*8+j]; B frag
// B[k=quad*8+j][n=lane&15]; C/D col=lane&15, row=quad*4+r (m89/m91-verified).
template<bool OUT_BF16, bool HAS_RESID>
__global__ __launch_bounds__(256) void gemm96_mfma(
    const unsigned short* __restrict__ A,
    const float* __restrict__ W,
    const float* __restrict__ bias,
    const float* __restrict__ resid,
    void* __restrict__ outv,
    int nStrips)
{
    __shared__ unsigned short Wt[96][104];  // [n][k] bf16, pad 104 (16B-aligned rows)
    const int tid = threadIdx.x;

    #pragma unroll
    for (int j = 0; j < 36; ++j) {          // 9216 = 256*36
        const int f = tid + 256 * j;
        const int k = f / 96, n = f - k * 96;
        Wt[n][k] = f2b(W[f]);
    }
    __syncthreads();

    const int lane = tid & 63;
    const int quad = lane >> 4;
    const int l16  = lane & 15;

    bf16x8 Bf[3][6];
    float  bv[6];
    #pragma unroll
    for (int ks = 0; ks < 3; ++ks)
        #pragma unroll
        for (int nt = 0; nt < 6; ++nt)
            Bf[ks][nt] = *(const bf16x8*)(&Wt[nt * 16 + l16][ks * 32 + quad * 8]);
    #pragma unroll
    for (int nt = 0; nt < 6; ++nt) bv[nt] = bias[nt * 16 + l16];

    const int gwave  = (blockIdx.x * 256 + tid) >> 6;
    const int nWaves = (gridDim.x * 256) >> 6;

    for (int strip = gwave; strip < nStrips; strip += nWaves) {
        const int row0 = strip * 16;
        const unsigned short* Ap = A + (size_t)(row0 + l16) * H + quad * 8;

        const bf16x8 Af0 = *(const bf16x8*)(Ap);
        const bf16x8 Af1 = *(const bf16x8*)(Ap + 32);
        const bf16x8 Af2 = *(const bf16x8*)(Ap + 64);

        floatx4 acc[6];
        #pragma unroll
        for (int nt = 0; nt < 6; ++nt) acc[nt] = (floatx4){0.f, 0.f, 0.f, 0.f};
        #pragma unroll
        for (int nt = 0; nt < 6; ++nt)
            acc[nt] = __builtin_amdgcn_mfma_f32_16x16x32_bf16(Af0, Bf[0][nt], acc[nt], 0, 0, 0);
        #pragma unroll
        for (int nt = 0; nt < 6; ++nt)
            acc[nt] = __builtin_amdgcn_mfma_f32_16x16x32_bf16(Af1, Bf[1][nt], acc[nt], 0, 0, 0);
        #pragma unroll
        for (int nt = 0; nt < 6; ++nt)
            acc[nt] = __builtin_amdgcn_mfma_f32_16x16x32_bf16(Af2, Bf[2][nt], acc[nt], 0, 0, 0);

        #pragma unroll
        for (int nt = 0; nt < 6; ++nt) {
            const int col = nt * 16 + l16;
            #pragma unroll
            for (int r = 0; r < 4; ++r) {
                const int row = row0 + quad * 4 + r;
                float g = gelu_erf(acc[nt][r] + bv[nt]);
                if (HAS_RESID) g += resid[(size_t)row * H + col];
                if (OUT_BF16) ((unsigned short*)outv)[(size_t)row * H + col] = f2b(g);
                else          ((float*)outv)[(size_t)row * H + col] = g;
            }
        }
    }
}

// ---------------- CSR build: histogram -> scan -> cursor scatter ------------
__global__ __launch_bounds__(256) void hist_deg(
    const int* __restrict__ dst, int* __restrict__ deg)
{
    const int e = blockIdx.x * 256 + threadIdx.x;
    if (e < EDGES) atomicAdd(&deg[dst[e]], 1);
}

__global__ __launch_bounds__(1024) void scan_deg(
    const int* __restrict__ deg, int* __restrict__ off, int* __restrict__ cursor)
{
    __shared__ int part[1024];
    const int tid = threadIdx.x;
    const int CH  = (NODES + 1023) / 1024;          // 49
    const int lo  = tid * CH;
    const int hi  = min(lo + CH, NODES);
    int s = 0;
    for (int i = lo; i < hi; ++i) s += deg[i];
    part[tid] = s;
    __syncthreads();
    for (int d = 1; d < 1024; d <<= 1) {
        int v = (tid >= d) ? part[tid - d] : 0;
        __syncthreads();
        part[tid] += v;
        __syncthreads();
    }
    int run = (tid == 0) ? 0 : part[tid - 1];
    for (int i = lo; i < hi; ++i) {
        off[i] = run; cursor[i] = run;
        run += deg[i];
    }
    if (tid == 1023) off[NODES] = part[1023];
}

__global__ __launch_bounds__(256) void build_csr(
    const int* __restrict__ dst, int* __restrict__ cursor, int* __restrict__ csr)
{
    const int e = blockIdx.x * 256 + threadIdx.x;
    if (e < EDGES) {
        const int p = atomicAdd(&cursor[dst[e]], 1);
        csr[p] = e;
    }
}

// ---------------- Pull-aggregate + residual: xb = x_feat + sum --------------
// 12 threads/node, 8 feats each. h is bf16; writes fp32 xb AND bf16 xb_bf.
__global__ __launch_bounds__(256) void gather_nodes(
    const unsigned short* __restrict__ h,
    const float* __restrict__ bases,
    const int* __restrict__ src,
    const int* __restrict__ off,
    const int* __restrict__ csr,
    const float* __restrict__ x_feat,
    float* __restrict__ xb,
    unsigned short* __restrict__ xb_bf)
{
    const int t = blockIdx.x * 256 + threadIdx.x;
    const int n = t / 12;
    const int seg = t - n * 12;
    if (n >= NODES) return;
    const int i0 = off[n], i1 = off[n + 1];
    const int so8 = seg * 8;

    floatx4 acc0 = (floatx4){0.f, 0.f, 0.f, 0.f};
    floatx4 acc1 = (floatx4){0.f, 0.f, 0.f, 0.f};
    for (int i = i0; i < i1; ++i) {
        const int e = csr[i];
        const int s = src[e];
        const size_t eo = (size_t)e * H + so8;
        const floatx4 b0 = *(const floatx4*)(bases + eo);
        const floatx4 b1 = *(const floatx4*)(bases + eo + 4);
        const ushort8 hv = *(const ushort8*)(h + (size_t)s * H + so8);
        #pragma unroll
        for (int j = 0; j < 4; ++j) acc0[j] = fmaf(b0[j], b2f(hv[j]),     acc0[j]);
        #pragma unroll
        for (int j = 0; j < 4; ++j) acc1[j] = fmaf(b1[j], b2f(hv[4 + j]), acc1[j]);
    }

    const size_t no = (size_t)n * H + so8;
    const floatx4 x0 = *(const floatx4*)(x_feat + no);
    const floatx4 x1 = *(const floatx4*)(x_feat + no + 4);
    #pragma unroll
    for (int j = 0; j < 4; ++j) { acc0[j] += x0[j]; acc1[j] += x1[j]; }
    *(floatx4*)(xb + no)     = acc0;
    *(floatx4*)(xb + no + 4) = acc1;
    ushort8 ob;
    #pragma unroll
    for (int j = 0; j < 4; ++j) { ob[j] = f2b(acc0[j]); ob[4 + j] = f2b(acc1[j]); }
    *(ushort8*)(xb_bf + no) = ob;
}

extern "C" void kernel_launch(void* const* d_in, const int* in_sizes, int n_in,
                              void* d_out, int out_size, void* d_ws, size_t ws_size,
                              hipStream_t stream)
{
    const float* x_feat = (const float*)d_in[0];
    const float* bases  = (const float*)d_in[1];
    const float* W_pre  = (const float*)d_in[2];
    const float* b_pre  = (const float*)d_in[3];
    const float* W1     = (const float*)d_in[4];
    const float* b1     = (const float*)d_in[5];
    const float* W2     = (const float*)d_in[6];
    const float* b2     = (const float*)d_in[7];
    const int* src = (const int*)d_in[8];
    const int* dst = (const int*)d_in[9];

    char* ws = (char*)d_ws;
    int*            deg    = (int*)(ws);
    int*            off    = (int*)(ws + 200192);
    int*            cursor = (int*)(ws + 400384);
    int*            csr    = (int*)(ws + 600576);
    unsigned short* xf_bf  = (unsigned short*)(ws + 3800576);   // 9.6 MB
    unsigned short* h_bf   = (unsigned short*)(ws + 13400576);  // 9.6 MB (reused as t_bf)
    float*          xb     = (float*)(ws + 23000576);           // 19.2 MB
    unsigned short* xb_bf  = (unsigned short*)(ws + 42200576);  // 9.6 MB
    unsigned short* t_bf   = h_bf;
    float*          out    = (float*)d_out;

    hipMemsetAsync(deg, 0, NODES * sizeof(int), stream);

    const int nStrips = NODES / 16;  // 3125 exact
    cvt_bf16<<<(NODES * H / 8 + 255) / 256, 256, 0, stream>>>(x_feat, xf_bf, NODES * H / 8);
    hist_deg<<<(EDGES + 255) / 256, 256, 0, stream>>>(dst, deg);
    scan_deg<<<1, 1024, 0, stream>>>(deg, off, cursor);
    build_csr<<<(EDGES + 255) / 256, 256, 0, stream>>>(dst, cursor, csr);
    // h = gelu(x @ W_pre + b_pre) -> bf16
    gemm96_mfma<true, false><<<512, 256, 0, stream>>>(xf_bf, W_pre, b_pre, nullptr, h_bf, nStrips);
    // xb = x_feat + pull-sum(h[src]*bases); also bf16 copy
    gather_nodes<<<(NODES * 12 + 255) / 256, 256, 0, stream>>>(
        h_bf, bases, src, off, csr, x_feat, xb, xb_bf);
    // t = gelu(xb @ W1 + b1) -> bf16
    gemm96_mfma<true, false><<<512, 256, 0, stream>>>(xb_bf, W1, b1, nullptr, t_bf, nStrips);
    // out = xb + gelu(t @ W2 + b2) -> fp32
    gemm96_mfma<false, true><<<512, 256, 0, stream>>>(t_bf, W2, b2, xb, out, nStrips);
}